// Round 13
// baseline (107.954 us; speedup 1.0000x reference)
//
#include <hip/hip_runtime.h>

#define THREADS 512
#define DIN 60
#define HN 256
#define DOUT 360

typedef __attribute__((ext_vector_type(8))) short short8;
typedef __attribute__((ext_vector_type(16))) float f32x16;
typedef __attribute__((ext_vector_type(4))) float f32x4;
typedef __attribute__((ext_vector_type(2))) float f32x2;
typedef __attribute__((ext_vector_type(4))) unsigned int u32x4;

__device__ __forceinline__ unsigned pk_bf16(float a, float b) {
    unsigned r;
    asm("v_cvt_pk_bf16_f32 %0, %1, %2" : "=v"(r) : "v"(a), "v"(b));
    return r;   // low16 = bf16(a), high16 = bf16(b)  (RNE)
}

// ---- load one 32-row x tile into fold-packed bf16 B-fragments (r10/r12-verified) ----
__device__ __forceinline__ void load_xtile(const float* __restrict__ x, int row0,
                                           int l31, int hi, short8 xb[4]) {
    const float* xr = x + (size_t)(row0 + l31) * DIN;
    f32x4 xa[4][2];
    #pragma unroll
    for (int kt = 0; kt < 4; ++kt) {
        int k0 = kt * 16 + hi * 8;
        xa[kt][0] = *(const f32x4*)(xr + k0);
        xa[kt][1] = (k0 + 4 < DIN) ? *(const f32x4*)(xr + k0 + 4) : (f32x4){0.f,0.f,0.f,0.f};
    }
    float p2 = 0.f;
    #pragma unroll
    for (int kt = 0; kt < 4; ++kt)
        #pragma unroll
        for (int h = 0; h < 2; ++h)
            #pragma unroll
            for (int i = 0; i < 4; ++i) p2 = fmaf(xa[kt][h][i], xa[kt][h][i], p2);
    float x2v = p2 + __shfl_xor(p2, 32);
    union { unsigned u; float f; } hb; hb.u = pk_bf16(x2v, 0.f) << 16;
    float x2lo = x2v - hb.f;
    #pragma unroll
    for (int kt = 0; kt < 4; ++kt) {
        union { u32x4 u; short8 s; } a;
        a.u[0] = pk_bf16(xa[kt][0][0], xa[kt][0][1]);
        a.u[1] = pk_bf16(xa[kt][0][2], xa[kt][0][3]);
        a.u[2] = pk_bf16(xa[kt][1][0], xa[kt][1][1]);
        a.u[3] = pk_bf16(xa[kt][1][2], xa[kt][1][3]);
        if (kt == 3) {   // hi lanes: k=60..63 B-side = {1, 1, x2hi, x2lo}
            a.u[2] = hi ? 0x3F803F80u : a.u[2];
            a.u[3] = hi ? pk_bf16(hb.f, x2lo) : a.u[3];
        }
        xb[kt] = a.s;
    }
}

// --- single fused kernel: per-block constant conversion -> LDS, then paired-tile pipeline ---
__global__ __launch_bounds__(THREADS, 2)
void rbf_main(const float* __restrict__ x, const float* __restrict__ centres,
              const float* __restrict__ sigmas, const float* __restrict__ W2,
              float* __restrict__ out)
{
    __shared__ short8 w2h[6144];                               // 96 KB (this col-half), [lrow][pc], pc=c^(lrow&31)
    __shared__ short8 cbf[2048];                               // 32 KB centres+fold, [row][p], p=c^(row&7)
    __shared__ __attribute__((aligned(16))) float nsl[HN];     // 1 KB m2ns2 = 2*sigma^2*log2e

    const int tid  = threadIdx.x;
    const int w    = tid >> 6;
    const int lane = tid & 63;
    const int l31  = lane & 31;
    const int hi   = lane >> 5;
    const int bid  = blockIdx.x;
    // XCD pair-swizzle: blocks bid and bid^8 share rows (same XCD), differ in col-half
    const int f     = (bid >> 3) & 1;
    const int sbase = (bid & 7) | ((bid >> 4) << 3);           // 0..127, bijective

    // ---- convert W2 half straight into swizzled LDS (prep logic, ws round-trip removed) ----
    #pragma unroll
    for (int i = 0; i < 12; ++i) {
        int tsk  = i * THREADS + tid;          // lrow*32 + pc
        int lrow = tsk >> 5, pc = tsk & 31;
        int c    = pc ^ (lrow & 31);
        int row  = f * 192 + lrow;
        union { u32x4 u; short8 s; } v; v.u = (u32x4){0u,0u,0u,0u};
        if (row < DOUT) {
            int rr = row / 12, jj = row % 12;
            int fcl = rr / 3, kk = rr % 3;
            int o = fcl * 36 + jj * 3 + kk;    // fold output col permutation
            const float* src = W2 + o * HN + c * 8;
            f32x4 a = *(const f32x4*)src, b = *(const f32x4*)(src + 4);
            v.u[0] = pk_bf16(a[0], a[1]); v.u[1] = pk_bf16(a[2], a[3]);
            v.u[2] = pk_bf16(b[0], b[1]); v.u[3] = pk_bf16(b[2], b[3]);
        }
        w2h[tsk] = v.s;
    }
    // ---- convert centres + fold slots ----
    #pragma unroll
    for (int i = 0; i < 4; ++i) {
        int tsk = i * THREADS + tid;           // row*8 + p
        int row = tsk >> 3, p = tsk & 7;
        int c   = p ^ (row & 7);
        const float* cr = centres + row * DIN;
        union { u32x4 u; short8 s; } v;
        if (c < 7) {
            f32x4 a = *(const f32x4*)(cr + c * 8), b = *(const f32x4*)(cr + c * 8 + 4);
            v.u[0] = pk_bf16(a[0], a[1]); v.u[1] = pk_bf16(a[2], a[3]);
            v.u[2] = pk_bf16(b[0], b[1]); v.u[3] = pk_bf16(b[2], b[3]);
        } else {   // k = 56..63: [c56..c59, -.5*c2hi, -.5*c2lo, -.5, -.5]
            f32x4 a = *(const f32x4*)(cr + 56);
            f32x4 s4 = (f32x4){0.f,0.f,0.f,0.f};
            #pragma unroll
            for (int q = 0; q < 15; ++q) {
                f32x4 t = *(const f32x4*)(cr + 4 * q);
                s4 += t * t;
            }
            float c2 = (s4[0] + s4[1]) + (s4[2] + s4[3]);
            union { unsigned u; float ff; } hb; hb.u = pk_bf16(c2, 0.f) << 16;
            float c2lo = c2 - hb.ff;
            v.u[0] = pk_bf16(a[0], a[1]); v.u[1] = pk_bf16(a[2], a[3]);
            v.u[2] = pk_bf16(-0.5f * hb.ff, -0.5f * c2lo);
            v.u[3] = pk_bf16(-0.5f, -0.5f);
        }
        cbf[tsk] = v.s;
    }
    if (tid < HN) {
        float sg = sigmas[tid];
        nsl[tid] = 2.f * sg * sg * 1.44269504088896340736f;
    }

    // ---- pit-0 x tiles loaded/packed BEFORE the barrier (hides x latency) ----
    const int rb0 = sbase * 1024 + w * 64;
    short8 xb0[4], xb1[4];
    load_xtile(x, rb0,      l31, hi, xb0);
    load_xtile(x, rb0 + 32, l31, hi, xb1);

    __syncthreads();   // LDS resident; no barriers, no LDS writes after this

    for (int pit = 0; pit < 2; ++pit) {
        const int rb = rb0 + pit * 512;
        if (pit) {
            load_xtile(x, rb,      l31, hi, xb0);
            load_xtile(x, rb + 32, l31, hi, xb1);
        }

        // ---- GEMM1 + phi: every cbf read feeds BOTH tiles ----
        unsigned pw0[32][2], pw1[32][2];
        #pragma unroll
        for (int h2 = 0; h2 < 2; ++h2) {
            f32x16 a0[4], a1v[4];
            #pragma unroll
            for (int nt = 0; nt < 4; ++nt) { a0[nt] = (f32x16){}; a1v[nt] = (f32x16){}; }
            __builtin_amdgcn_s_setprio(1);
            #pragma unroll
            for (int nt = 0; nt < 4; ++nt) {
                int row = (h2 * 4 + nt) * 32 + l31;
                #pragma unroll
                for (int kt = 0; kt < 4; ++kt) {
                    short8 cf = cbf[row * 8 + ((kt * 2 + hi) ^ (row & 7))];
                    a0[nt]  = __builtin_amdgcn_mfma_f32_32x32x16_bf16(cf, xb0[kt], a0[nt], 0, 0, 0);
                    a1v[nt] = __builtin_amdgcn_mfma_f32_32x32x16_bf16(cf, xb1[kt], a1v[nt], 0, 0, 0);
                }
            }
            __builtin_amdgcn_s_setprio(0);
            // phi = exp2(min(m2ns2 * S, 0)); ns4 shared across the pair
            #pragma unroll
            for (int nt = 0; nt < 4; ++nt) {
                int ntg = h2 * 4 + nt;
                #pragma unroll
                for (int q = 0; q < 4; ++q) {
                    f32x4 ns4 = *(const f32x4*)(nsl + ntg * 32 + 8 * q + 4 * hi);
                    float p0[4], p1[4];
                    #pragma unroll
                    for (int j = 0; j < 4; ++j) {
                        p0[j] = exp2f(fminf(ns4[j] * a0[nt][4 * q + j],  0.f));
                        p1[j] = exp2f(fminf(ns4[j] * a1v[nt][4 * q + j], 0.f));
                    }
                    pw0[ntg * 4 + q][0] = pk_bf16(p0[0], p0[1]);
                    pw0[ntg * 4 + q][1] = pk_bf16(p0[2], p0[3]);
                    pw1[ntg * 4 + q][0] = pk_bf16(p1[0], p1[1]);
                    pw1[ntg * 4 + q][1] = pk_bf16(p1[2], p1[3]);
                }
            }
        }

        // ---- GEMM2: every w2h read feeds both tiles; B-frags via permlane32_swap ----
        // v_permlane32_swap_b32 vdst, vsrc: vdst.row1 <-> vsrc.row0.
        // vdst = pw[2kt] (low k-tile), vsrc = pw[2kt+1] (high): vdst' = u[0]/u[1], vsrc' = u[2]/u[3].
        #pragma unroll
        for (int pass = 0; pass < 2; ++pass) {
            f32x16 c0[3], c1[3];
            #pragma unroll
            for (int nt = 0; nt < 3; ++nt) { c0[nt] = (f32x16){}; c1[nt] = (f32x16){}; }

            #pragma unroll
            for (int kt = 0; kt < 16; ++kt) {
                unsigned d00 = pw0[2 * kt][0], s00 = pw0[2 * kt + 1][0];
                unsigned d01 = pw0[2 * kt][1], s01 = pw0[2 * kt + 1][1];
                asm("v_permlane32_swap_b32 %0, %1" : "+v"(d00), "+v"(s00));
                asm("v_permlane32_swap_b32 %0, %1" : "+v"(d01), "+v"(s01));
                unsigned d10 = pw1[2 * kt][0], s10 = pw1[2 * kt + 1][0];
                unsigned d11 = pw1[2 * kt][1], s11 = pw1[2 * kt + 1][1];
                asm("v_permlane32_swap_b32 %0, %1" : "+v"(d10), "+v"(s10));
                asm("v_permlane32_swap_b32 %0, %1" : "+v"(d11), "+v"(s11));
                union { u32x4 u; short8 s; } b0, b1;
                b0.u[0] = d00; b0.u[1] = d01; b0.u[2] = s00; b0.u[3] = s01;
                b1.u[0] = d10; b1.u[1] = d11; b1.u[2] = s10; b1.u[3] = s11;

                __builtin_amdgcn_s_setprio(1);
                #pragma unroll
                for (int nt = 0; nt < 3; ++nt) {
                    int lrow = (pass * 3 + nt) * 32 + l31;
                    short8 wf = w2h[lrow * 32 + ((kt * 2 + hi) ^ l31)];
                    c0[nt] = __builtin_amdgcn_mfma_f32_32x32x16_bf16(wf, b0.s, c0[nt], 0, 0, 0);
                    c1[nt] = __builtin_amdgcn_mfma_f32_32x32x16_bf16(wf, b1.s, c1[nt], 0, 0, 0);
                }
                __builtin_amdgcn_s_setprio(0);
            }

            // ---- stores: f32x4 chunks, columns already in final permuted order ----
            #pragma unroll
            for (int t = 0; t < 2; ++t) {
                float* op = out + (size_t)(rb + t * 32 + l31) * DOUT;
                #pragma unroll
                for (int nt = 0; nt < 3; ++nt) {
                    const f32x16& cc = t ? c1[nt] : c0[nt];
                    #pragma unroll
                    for (int q = 0; q < 4; ++q) {
                        int col = f * 192 + pass * 96 + nt * 32 + q * 8 + hi * 4;
                        if (col < DOUT) {
                            f32x4 v;
                            v[0] = cc[4 * q + 0]; v[1] = cc[4 * q + 1];
                            v[2] = cc[4 * q + 2]; v[3] = cc[4 * q + 3];
                            *(f32x4*)(op + col) = v;
                        }
                    }
                }
            }
        }
    }
}

extern "C" void kernel_launch(void* const* d_in, const int* in_sizes, int n_in,
                              void* d_out, int out_size, void* d_ws, size_t ws_size,
                              hipStream_t stream) {
    const float* x       = (const float*)d_in[0];
    const float* centres = (const float*)d_in[1];
    const float* sigmas  = (const float*)d_in[2];
    const float* W2      = (const float*)d_in[3];
    float* out = (float*)d_out;
    rbf_main<<<dim3(256), dim3(THREADS), 0, stream>>>(x, centres, sigmas, W2, out);
}

// Round 14
// 97.297 us; speedup vs baseline: 1.1095x; 1.1095x over previous
//
#include <hip/hip_runtime.h>

#define THREADS 512
#define DIN 60
#define HN 256
#define DOUT 360

typedef __attribute__((ext_vector_type(8))) short short8;
typedef __attribute__((ext_vector_type(16))) float f32x16;
typedef __attribute__((ext_vector_type(4))) float f32x4;
typedef __attribute__((ext_vector_type(2))) float f32x2;
typedef __attribute__((ext_vector_type(4))) unsigned int u32x4;

// d_ws layout (bytes); total 231424 B
#define WS_CBF   0            // 2048 * 16 B = 32768  (centres bf16 + fold slots, [row][p], p=c^(row&7))
#define WS_CN    32768        // 256 floats m2ns2 = 2*sigma^2*log2e (1024 B)
#define WS_W2    34816        // [row 0..383][pc 0..31] short8, pc=c^(row&31) = 196608 B

__device__ __forceinline__ short bf16_bits(float f) {   // prep-side only
    union { float f; unsigned u; } v; v.f = f;
    unsigned r = (v.u + 0x7FFFu + ((v.u >> 16) & 1u)) >> 16;
    return (short)(unsigned short)r;
}

__device__ __forceinline__ unsigned pk_bf16(float a, float b) {
    unsigned r;
    asm("v_cvt_pk_bf16_f32 %0, %1, %2" : "=v"(r) : "v"(a), "v"(b));
    return r;   // low16 = bf16(a), high16 = bf16(b)
}

__device__ __forceinline__ void gload16(const void* g, void* lds) {
    __builtin_amdgcn_global_load_lds(
        (const __attribute__((address_space(1))) unsigned int*)(uintptr_t)g,
        (__attribute__((address_space(3))) unsigned int*)(unsigned int)(uintptr_t)lds,
        16, 0, 0);
}

// ---------------- prep: convert/permute constants into ws ----------------
__global__ void prep(const float* __restrict__ centres, const float* __restrict__ sigmas,
                     const float* __restrict__ W2, short* __restrict__ ws)
{
    int t = blockIdx.x * 256 + threadIdx.x;
    if (t < 12288) {
        // W2: [row 0..383][pc 0..31] short8; pc = c ^ (row&31); k = c*8..c*8+7
        int row = t >> 5, pc = t & 31;
        int c = pc ^ (row & 31);
        short8 v = {0,0,0,0,0,0,0,0};
        if (row < DOUT) {
            int rr = row / 12, jj = row % 12;
            int fcl = rr / 3, kk = rr % 3;
            int o = fcl * 36 + jj * 3 + kk;            // fold output col permutation
            const float* src = W2 + o * HN + c * 8;
            #pragma unroll
            for (int i = 0; i < 8; ++i) v[i] = bf16_bits(src[i]);
        }
        *(short8*)(ws + (WS_W2 / 2) + t * 8) = v;
    } else if (t < 14336) {
        // centres bf16 + fold slots: [row][p 0..7], p = c ^ (row&7)
        // k<60: c_k ; k=60: -0.5*c2hi ; k=61: -0.5*c2lo ; k=62,63: -0.5
        int j = t - 12288;
        int row = j >> 3, p = j & 7;
        int c = p ^ (row & 7);
        short8 v = {0,0,0,0,0,0,0,0};
        const float* cr = centres + row * DIN;
        if (c < 7) {
            #pragma unroll
            for (int i = 0; i < 8; ++i) {
                int k = c * 8 + i;
                if (k < DIN) v[i] = bf16_bits(cr[k]);
            }
        } else {   // k = 56..63
            #pragma unroll
            for (int i = 0; i < 4; ++i) v[i] = bf16_bits(cr[56 + i]);
            float c2 = 0.f;
            #pragma unroll
            for (int d = 0; d < DIN; ++d) c2 = fmaf(cr[d], cr[d], c2);
            union { unsigned u; float f; } hb;
            hb.u = ((unsigned)(unsigned short)bf16_bits(c2)) << 16;
            float c2lo = c2 - hb.f;
            v[4] = bf16_bits(-0.5f * hb.f);
            v[5] = bf16_bits(-0.5f * c2lo);
            v[6] = bf16_bits(-0.5f);
            v[7] = bf16_bits(-0.5f);
        }
        *(short8*)(ws + (WS_CBF / 2) + j * 8) = v;
    } else if (t < 14592) {
        int i = t - 14336;
        float sg = sigmas[i];
        ((float*)ws)[WS_CN / 4 + i] = 2.f * sg * sg * 1.44269504088896340736f;  // m2ns2
    }
}

// ---- load one 32-row x tile into fold-packed bf16 B-fragments (r10/r12-verified) ----
__device__ __forceinline__ void load_xtile(const float* __restrict__ x, int row0,
                                           int l31, int hi, short8 xb[4]) {
    const float* xr = x + (size_t)(row0 + l31) * DIN;
    f32x4 xa[4][2];
    #pragma unroll
    for (int kt = 0; kt < 4; ++kt) {
        int k0 = kt * 16 + hi * 8;
        xa[kt][0] = *(const f32x4*)(xr + k0);
        xa[kt][1] = (k0 + 4 < DIN) ? *(const f32x4*)(xr + k0 + 4) : (f32x4){0.f,0.f,0.f,0.f};
    }
    float p2 = 0.f;
    #pragma unroll
    for (int kt = 0; kt < 4; ++kt)
        #pragma unroll
        for (int h = 0; h < 2; ++h)
            #pragma unroll
            for (int i = 0; i < 4; ++i) p2 = fmaf(xa[kt][h][i], xa[kt][h][i], p2);
    float x2v = p2 + __shfl_xor(p2, 32);
    union { unsigned u; float f; } hb; hb.u = pk_bf16(x2v, 0.f) << 16;
    float x2lo = x2v - hb.f;
    #pragma unroll
    for (int kt = 0; kt < 4; ++kt) {
        union { u32x4 u; short8 s; } a;
        a.u[0] = pk_bf16(xa[kt][0][0], xa[kt][0][1]);
        a.u[1] = pk_bf16(xa[kt][0][2], xa[kt][0][3]);
        a.u[2] = pk_bf16(xa[kt][1][0], xa[kt][1][1]);
        a.u[3] = pk_bf16(xa[kt][1][2], xa[kt][1][3]);
        if (kt == 3) {   // hi lanes: k=60..63 B-side = {1, 1, x2hi, x2lo}
            a.u[2] = hi ? 0x3F803F80u : a.u[2];
            a.u[3] = hi ? pk_bf16(hb.f, x2lo) : a.u[3];
        }
        xb[kt] = a.s;
    }
}

// --- main: r12 structure, register-pressure-reduced (GEMM1 4x2 chunks, GEMM2 3x2 passes) ---
__global__ __launch_bounds__(THREADS, 2)
void rbf_main(const float* __restrict__ x, const short* __restrict__ ws,
              float* __restrict__ out)
{
    __shared__ short8 w2h[6144];                               // 96 KB (this col-half)
    __shared__ short8 cbf[2048];                               // 32 KB centres+fold
    __shared__ __attribute__((aligned(16))) float nsl[HN];     // 1 KB m2ns2

    const int tid  = threadIdx.x;
    const int w    = tid >> 6;
    const int lane = tid & 63;
    const int l31  = lane & 31;
    const int hi   = lane >> 5;
    const int bid  = blockIdx.x;
    // XCD pair-swizzle: blocks bid and bid^8 share rows (same XCD), differ in col-half
    const int f     = (bid >> 3) & 1;
    const int sbase = (bid & 7) | ((bid >> 4) << 3);           // 0..127, bijective

    // ---- stage everything once (async DMA), one barrier total ----
    #pragma unroll
    for (int i = 0; i < 12; ++i)
        gload16(ws + (WS_W2 / 2) + ((size_t)f * 6144 + i * THREADS + tid) * 8,
                (char*)w2h + (i * THREADS + tid) * 16);
    #pragma unroll
    for (int i = 0; i < 4; ++i)
        gload16(ws + (WS_CBF / 2) + (i * THREADS + tid) * 8, (char*)cbf + (i * THREADS + tid) * 16);
    if (tid < 64)
        gload16(ws + (WS_CN / 2) + tid * 8, (char*)nsl + tid * 16);

    // ---- pit-0 x tiles loaded/packed BEFORE the barrier (hides x latency) ----
    const int rb0 = sbase * 1024 + w * 64;
    short8 xb0[4], xb1[4];
    load_xtile(x, rb0,      l31, hi, xb0);
    load_xtile(x, rb0 + 32, l31, hi, xb1);

    __syncthreads();   // LDS resident; no barriers, no LDS writes after this

    for (int pit = 0; pit < 2; ++pit) {
        const int rb = rb0 + pit * 512;
        if (pit) {
            load_xtile(x, rb,      l31, hi, xb0);
            load_xtile(x, rb + 32, l31, hi, xb1);
        }

        // ---- GEMM1 + phi in 4 chunks of 2 N-tiles (acc = 64 regs, not 128) ----
        unsigned pw0[32][2], pw1[32][2];
        #pragma unroll
        for (int ch = 0; ch < 4; ++ch) {
            f32x16 a0[2], a1v[2];
            #pragma unroll
            for (int nt = 0; nt < 2; ++nt) { a0[nt] = (f32x16){}; a1v[nt] = (f32x16){}; }
            __builtin_amdgcn_s_setprio(1);
            #pragma unroll
            for (int nt = 0; nt < 2; ++nt) {
                int row = (ch * 2 + nt) * 32 + l31;
                #pragma unroll
                for (int kt = 0; kt < 4; ++kt) {
                    short8 cf = cbf[row * 8 + ((kt * 2 + hi) ^ (row & 7))];
                    a0[nt]  = __builtin_amdgcn_mfma_f32_32x32x16_bf16(cf, xb0[kt], a0[nt], 0, 0, 0);
                    a1v[nt] = __builtin_amdgcn_mfma_f32_32x32x16_bf16(cf, xb1[kt], a1v[nt], 0, 0, 0);
                }
            }
            __builtin_amdgcn_s_setprio(0);
            // phi = exp2(min(m2ns2 * S, 0)); ns4 shared across the pair
            #pragma unroll
            for (int nt = 0; nt < 2; ++nt) {
                int ntg = ch * 2 + nt;
                #pragma unroll
                for (int q = 0; q < 4; ++q) {
                    f32x4 ns4 = *(const f32x4*)(nsl + ntg * 32 + 8 * q + 4 * hi);
                    float p0[4], p1[4];
                    #pragma unroll
                    for (int j = 0; j < 4; ++j) {
                        p0[j] = exp2f(fminf(ns4[j] * a0[nt][4 * q + j],  0.f));
                        p1[j] = exp2f(fminf(ns4[j] * a1v[nt][4 * q + j], 0.f));
                    }
                    pw0[ntg * 4 + q][0] = pk_bf16(p0[0], p0[1]);
                    pw0[ntg * 4 + q][1] = pk_bf16(p0[2], p0[3]);
                    pw1[ntg * 4 + q][0] = pk_bf16(p1[0], p1[1]);
                    pw1[ntg * 4 + q][1] = pk_bf16(p1[2], p1[3]);
                }
            }
        }

        // ---- GEMM2 in 3 passes of 2 N-tiles (acc = 64 regs, not 96) ----
        // v_permlane32_swap_b32 vdst, vsrc: vdst.row1 <-> vsrc.row0.
        // vdst = pw[2kt] (low k-tile), vsrc = pw[2kt+1] (high): vdst' = u[0]/u[1], vsrc' = u[2]/u[3].
        #pragma unroll
        for (int pass = 0; pass < 3; ++pass) {
            f32x16 c0[2], c1[2];
            #pragma unroll
            for (int nt = 0; nt < 2; ++nt) { c0[nt] = (f32x16){}; c1[nt] = (f32x16){}; }

            #pragma unroll
            for (int kt = 0; kt < 16; ++kt) {
                unsigned d00 = pw0[2 * kt][0], s00 = pw0[2 * kt + 1][0];
                unsigned d01 = pw0[2 * kt][1], s01 = pw0[2 * kt + 1][1];
                asm("v_permlane32_swap_b32 %0, %1" : "+v"(d00), "+v"(s00));
                asm("v_permlane32_swap_b32 %0, %1" : "+v"(d01), "+v"(s01));
                unsigned d10 = pw1[2 * kt][0], s10 = pw1[2 * kt + 1][0];
                unsigned d11 = pw1[2 * kt][1], s11 = pw1[2 * kt + 1][1];
                asm("v_permlane32_swap_b32 %0, %1" : "+v"(d10), "+v"(s10));
                asm("v_permlane32_swap_b32 %0, %1" : "+v"(d11), "+v"(s11));
                union { u32x4 u; short8 s; } b0, b1;
                b0.u[0] = d00; b0.u[1] = d01; b0.u[2] = s00; b0.u[3] = s01;
                b1.u[0] = d10; b1.u[1] = d11; b1.u[2] = s10; b1.u[3] = s11;

                __builtin_amdgcn_s_setprio(1);
                #pragma unroll
                for (int nt = 0; nt < 2; ++nt) {
                    int lrow = (pass * 2 + nt) * 32 + l31;
                    short8 wf = w2h[lrow * 32 + ((kt * 2 + hi) ^ l31)];
                    c0[nt] = __builtin_amdgcn_mfma_f32_32x32x16_bf16(wf, b0.s, c0[nt], 0, 0, 0);
                    c1[nt] = __builtin_amdgcn_mfma_f32_32x32x16_bf16(wf, b1.s, c1[nt], 0, 0, 0);
                }
                __builtin_amdgcn_s_setprio(0);
            }

            // ---- stores: f32x4 chunks, columns already in final permuted order ----
            #pragma unroll
            for (int t = 0; t < 2; ++t) {
                float* op = out + (size_t)(rb + t * 32 + l31) * DOUT;
                #pragma unroll
                for (int nt = 0; nt < 2; ++nt) {
                    const f32x16& cc = t ? c1[nt] : c0[nt];
                    #pragma unroll
                    for (int q = 0; q < 4; ++q) {
                        int col = f * 192 + pass * 64 + nt * 32 + q * 8 + hi * 4;
                        if (col < DOUT) {
                            f32x4 v;
                            v[0] = cc[4 * q + 0]; v[1] = cc[4 * q + 1];
                            v[2] = cc[4 * q + 2]; v[3] = cc[4 * q + 3];
                            *(f32x4*)(op + col) = v;
                        }
                    }
                }
            }
        }
    }
}

extern "C" void kernel_launch(void* const* d_in, const int* in_sizes, int n_in,
                              void* d_out, int out_size, void* d_ws, size_t ws_size,
                              hipStream_t stream) {
    const float* x       = (const float*)d_in[0];
    const float* centres = (const float*)d_in[1];
    const float* sigmas  = (const float*)d_in[2];
    const float* W2      = (const float*)d_in[3];
    float* out = (float*)d_out;
    short* ws  = (short*)d_ws;                  // needs 231424 B
    prep<<<dim3(57), dim3(256), 0, stream>>>(centres, sigmas, W2, ws);
    rbf_main<<<dim3(256), dim3(THREADS), 0, stream>>>(x, ws, out);
}

// Round 15
// 81.550 us; speedup vs baseline: 1.3238x; 1.1931x over previous
//
#include <hip/hip_runtime.h>

#define THREADS 512
#define DIN 60
#define HN 256
#define DOUT 360

typedef __attribute__((ext_vector_type(8))) short short8;
typedef __attribute__((ext_vector_type(4))) float f32x4;
typedef __attribute__((ext_vector_type(4))) unsigned int u32x4;

// d_ws layout (bytes); total 229376 B
#define WS_CBF   0            // 2048 * 16 B = 32768  (nsq-scaled centres + fold, [row][p], p=c^(row&7))
#define WS_W2    32768        // [row 0..383][pc 0..31] short8, pc=c^(row&7) = 196608 B

__device__ __forceinline__ short bf16_bits(float f) {   // prep-side only
    union { float f; unsigned u; } v; v.f = f;
    unsigned r = (v.u + 0x7FFFu + ((v.u >> 16) & 1u)) >> 16;
    return (short)(unsigned short)r;
}

__device__ __forceinline__ unsigned pk_bf16(float a, float b) {
    unsigned r;
    asm("v_cvt_pk_bf16_f32 %0, %1, %2" : "=v"(r) : "v"(a), "v"(b));
    return r;   // low16 = bf16(a), high16 = bf16(b)
}

__device__ __forceinline__ void gload16(const void* g, void* lds) {
    __builtin_amdgcn_global_load_lds(
        (const __attribute__((address_space(1))) unsigned int*)(uintptr_t)g,
        (__attribute__((address_space(3))) unsigned int*)(unsigned int)(uintptr_t)lds,
        16, 0, 0);
}

// ---------------- prep: convert/permute constants into ws ----------------
__global__ void prep(const float* __restrict__ centres, const float* __restrict__ sigmas,
                     const float* __restrict__ W2, short* __restrict__ ws)
{
    int t = blockIdx.x * 256 + threadIdx.x;
    if (t < 12288) {
        // W2: [row 0..383][pc 0..31] short8; pc = c ^ (row&7); k = c*8..c*8+7
        int row = t >> 5, pc = t & 31;
        int c = pc ^ (row & 7);
        short8 v = {0,0,0,0,0,0,0,0};
        if (row < DOUT) {
            int rr = row / 12, jj = row % 12;
            int fcl = rr / 3, kk = rr % 3;
            int o = fcl * 36 + jj * 3 + kk;            // fold output col permutation
            const float* src = W2 + o * HN + c * 8;
            #pragma unroll
            for (int i = 0; i < 8; ++i) v[i] = bf16_bits(src[i]);
        }
        *(short8*)(ws + (WS_W2 / 2) + t * 8) = v;
    } else if (t < 14336) {
        // cbf: nsq-scaled centres + fold: [row][p 0..7], p = c ^ (row&7)
        // k<60: nsq*c_k ; k=60,61: hi/lo of -0.5*nsq*c2 (b=1) ; k=62,63: -0.5*nsq (b=x2hi/x2lo)
        int j = t - 12288;
        int row = j >> 3, p = j & 7;
        int c = p ^ (row & 7);
        const float* cr = centres + row * DIN;
        float sg = sigmas[row];
        union { unsigned u; float f; } nq;
        nq.u = ((unsigned)(unsigned short)bf16_bits(2.f * sg * sg * 1.44269504088896340736f)) << 16;
        const float nsq = nq.f;                        // bf16-exact ns
        short8 v = {0,0,0,0,0,0,0,0};
        if (c < 7) {
            #pragma unroll
            for (int i = 0; i < 8; ++i) {
                int k = c * 8 + i;
                if (k < DIN) v[i] = bf16_bits(nsq * cr[k]);
            }
        } else {   // k = 56..63
            #pragma unroll
            for (int i = 0; i < 4; ++i) v[i] = bf16_bits(nsq * cr[56 + i]);
            float c2 = 0.f;
            #pragma unroll
            for (int d = 0; d < DIN; ++d) c2 = fmaf(cr[d], cr[d], c2);
            float T = -0.5f * nsq * c2;
            union { unsigned u; float f; } th;
            th.u = ((unsigned)(unsigned short)bf16_bits(T)) << 16;   // T_hi (bf16-exact)
            v[4] = bf16_bits(th.f);            // == bf16 of T_hi, exact
            v[5] = bf16_bits(T - th.f);        // T_lo
            v[6] = bf16_bits(-0.5f * nsq);     // exact (exponent shift of bf16 value)
            v[7] = v[6];
        }
        *(short8*)(ws + (WS_CBF / 2) + j * 8) = v;
    }
}

// ---- one 16-row x tile -> fold-packed bf16 B-fragments (16x16 layout, r7-verified) ----
__device__ __forceinline__ void load_xtile16(const float* __restrict__ x, int row0,
                                             int l15, int g, short8 xb[2]) {
    const float* xr = x + (size_t)(row0 + l15) * DIN;
    f32x4 xa[2][2];
    #pragma unroll
    for (int kt = 0; kt < 2; ++kt) {
        int k0 = kt * 32 + g * 8;
        xa[kt][0] = *(const f32x4*)(xr + k0);
        xa[kt][1] = (k0 + 4 < DIN) ? *(const f32x4*)(xr + k0 + 4) : (f32x4){0.f,0.f,0.f,0.f};
    }
    float p2 = 0.f;
    #pragma unroll
    for (int kt = 0; kt < 2; ++kt)
        #pragma unroll
        for (int h = 0; h < 2; ++h)
            #pragma unroll
            for (int i = 0; i < 4; ++i) p2 = fmaf(xa[kt][h][i], xa[kt][h][i], p2);
    p2 += __shfl_xor(p2, 16);
    p2 += __shfl_xor(p2, 32);
    union { unsigned u; float f; } hb; hb.u = pk_bf16(p2, 0.f) << 16;  // x2hi (bf16-exact)
    float x2lo = p2 - hb.f;
    #pragma unroll
    for (int kt = 0; kt < 2; ++kt) {
        union { u32x4 u; short8 s; } a;
        a.u[0] = pk_bf16(xa[kt][0][0], xa[kt][0][1]);
        a.u[1] = pk_bf16(xa[kt][0][2], xa[kt][0][3]);
        a.u[2] = pk_bf16(xa[kt][1][0], xa[kt][1][1]);
        a.u[3] = pk_bf16(xa[kt][1][2], xa[kt][1][3]);
        if (kt == 1 && g == 3) {   // k=60..63: b = {1, 1, x2hi, x2lo}
            a.u[2] = 0x3F803F80u;
            a.u[3] = pk_bf16(hb.f, x2lo);
        }
        xb[kt] = a.s;
    }
}

// --- main: 512 blocks x 512 thr, 2 blocks/CU (80 KB LDS), 4 waves/SIMD, 16x16 MFMA ---
__global__ __launch_bounds__(THREADS, 4)
void rbf_main(const float* __restrict__ x, const short* __restrict__ ws,
              float* __restrict__ out)
{
    __shared__ short8 w2q[3072];     // 48 KB: 96 rows x 32 chunks (this col-quarter)
    __shared__ short8 cbf[2048];     // 32 KB: nsq-scaled centres + fold

    const int tid  = threadIdx.x;
    const int w    = tid >> 6;
    const int lane = tid & 63;
    const int l15  = lane & 15;
    const int g    = lane >> 4;
    const int bid  = blockIdx.x;
    // XCD swizzle: the 4 col-quarters of the same rows land on the same XCD (bid%8 pres.)
    const int q     = (bid >> 3) & 3;                    // col quarter [q*96, q*96+96)
    const int sbase = (bid & 7) | ((bid >> 5) << 3);     // 0..127, bijective

    // ---- stage W2 quarter + cbf once (async DMA), one barrier total ----
    #pragma unroll
    for (int i = 0; i < 6; ++i)
        gload16(ws + (WS_W2 / 2) + ((size_t)q * 3072 + i * THREADS + tid) * 8,
                (char*)w2q + (i * THREADS + tid) * 16);
    #pragma unroll
    for (int i = 0; i < 4; ++i)
        gload16(ws + (WS_CBF / 2) + (i * THREADS + tid) * 8, (char*)cbf + (i * THREADS + tid) * 16);

    __syncthreads();   // LDS resident; no barriers, no LDS writes after this

    for (int it = 0; it < 8; ++it) {
        const int rbase = sbase * 1024 + it * 128 + w * 16;

        short8 xb[2];
        load_xtile16(x, rbase, l15, g, xb);

        // ---- GEMM1 + phi in 2 halves of 8 N-tiles (acc = 32 regs) ----
        // S = -0.5*nsq*d2 complete from MFMA (ns-fold); phi = exp2(min(S,0))
        unsigned pw[16][2];
        #pragma unroll
        for (int h2 = 0; h2 < 2; ++h2) {
            f32x4 acc1[8];
            #pragma unroll
            for (int nt = 0; nt < 8; ++nt) acc1[nt] = (f32x4){0.f, 0.f, 0.f, 0.f};
            __builtin_amdgcn_s_setprio(1);
            #pragma unroll
            for (int nt = 0; nt < 8; ++nt) {
                int row = (h2 * 8 + nt) * 16 + l15;
                #pragma unroll
                for (int kt = 0; kt < 2; ++kt) {
                    short8 cf = cbf[row * 8 + ((kt * 4 + g) ^ (row & 7))];
                    acc1[nt] = __builtin_amdgcn_mfma_f32_16x16x32_bf16(cf, xb[kt], acc1[nt], 0, 0, 0);
                }
            }
            __builtin_amdgcn_s_setprio(0);
            #pragma unroll
            for (int nt = 0; nt < 8; ++nt) {
                int ntg = h2 * 8 + nt;
                float ph[4];
                #pragma unroll
                for (int r = 0; r < 4; ++r)
                    ph[r] = exp2f(fminf(acc1[nt][r], 0.f));
                pw[ntg][0] = pk_bf16(ph[0], ph[1]);
                pw[ntg][1] = pk_bf16(ph[2], ph[3]);
            }
        }

        // ---- GEMM2: A=phi (r7-verified shuffle transpose), B=W2 quarter. 6 nt x 8 kt ----
        f32x4 acc2[6];
        #pragma unroll
        for (int nt = 0; nt < 6; ++nt) acc2[nt] = (f32x4){0.f, 0.f, 0.f, 0.f};

        const int s0 = l15 + ((g & 1) << 5);
        const bool hi = (g >= 2);

        #pragma unroll
        for (int kt = 0; kt < 8; ++kt) {
            int A0 = __shfl((int)pw[2*kt][0],   s0);
            int A1 = __shfl((int)pw[2*kt][1],   s0);
            int C0 = __shfl((int)pw[2*kt+1][0], s0);
            int C1 = __shfl((int)pw[2*kt+1][1], s0);
            int B0 = __shfl((int)pw[2*kt][0],   s0 + 16);
            int B1 = __shfl((int)pw[2*kt][1],   s0 + 16);
            int D0 = __shfl((int)pw[2*kt+1][0], s0 + 16);
            int D1 = __shfl((int)pw[2*kt+1][1], s0 + 16);
            union { u32x4 u; short8 s; } afu;
            afu.u[0] = (unsigned)(hi ? C0 : A0);
            afu.u[1] = (unsigned)(hi ? C1 : A1);
            afu.u[2] = (unsigned)(hi ? D0 : B0);
            afu.u[3] = (unsigned)(hi ? D1 : B1);

            __builtin_amdgcn_s_setprio(1);
            #pragma unroll
            for (int nt = 0; nt < 6; ++nt) {
                int lrow = nt * 16 + l15;
                short8 bf = w2q[lrow * 32 + ((kt * 4 + g) ^ (lrow & 7))];
                acc2[nt] = __builtin_amdgcn_mfma_f32_16x16x32_bf16(afu.s, bf, acc2[nt], 0, 0, 0);
            }
            __builtin_amdgcn_s_setprio(0);
        }

        // ---- store: col = q*96 + nt*16 + l15, rows g*4+r (r7-verified) ----
        const int orow = rbase + g * 4;
        #pragma unroll
        for (int nt = 0; nt < 6; ++nt) {
            int col = q * 96 + nt * 16 + l15;
            if (col < DOUT) {
                #pragma unroll
                for (int r = 0; r < 4; ++r)
                    out[(size_t)(orow + r) * DOUT + col] = acc2[nt][r];
            }
        }
    }
}

extern "C" void kernel_launch(void* const* d_in, const int* in_sizes, int n_in,
                              void* d_out, int out_size, void* d_ws, size_t ws_size,
                              hipStream_t stream) {
    const float* x       = (const float*)d_in[0];
    const float* centres = (const float*)d_in[1];
    const float* sigmas  = (const float*)d_in[2];
    const float* W2      = (const float*)d_in[3];
    float* out = (float*)d_out;
    short* ws  = (short*)d_ws;                  // needs 229376 B
    prep<<<dim3(56), dim3(256), 0, stream>>>(centres, sigmas, W2, ws);
    rbf_main<<<dim3(512), dim3(THREADS), 0, stream>>>(x, ws, out);
}

// Round 16
// 63.115 us; speedup vs baseline: 1.7104x; 1.2921x over previous
//
#include <hip/hip_runtime.h>

#define THREADS 512
#define DIN 60
#define HN 256
#define DOUT 360

typedef __attribute__((ext_vector_type(8))) short short8;
typedef __attribute__((ext_vector_type(16))) float f32x16;
typedef __attribute__((ext_vector_type(4))) float f32x4;
typedef __attribute__((ext_vector_type(4))) unsigned int u32x4;

// d_ws layout (bytes); total 229376 B
#define WS_CBF   0            // 2048 * 16 B = 32768  (ns-scaled centres + fold, [row][p], p=c^(row&7))
#define WS_W2    32768        // [row 0..383][pc 0..31] short8, pc=c^(row&31) = 196608 B

__device__ __forceinline__ short bf16_bits(float f) {   // prep-side only
    union { float f; unsigned u; } v; v.f = f;
    unsigned r = (v.u + 0x7FFFu + ((v.u >> 16) & 1u)) >> 16;
    return (short)(unsigned short)r;
}

__device__ __forceinline__ unsigned pk_bf16(float a, float b) {
    unsigned r;
    asm("v_cvt_pk_bf16_f32 %0, %1, %2" : "=v"(r) : "v"(a), "v"(b));
    return r;   // low16 = bf16(a), high16 = bf16(b)
}

__device__ __forceinline__ void gload16(const void* g, void* lds) {
    __builtin_amdgcn_global_load_lds(
        (const __attribute__((address_space(1))) unsigned int*)(uintptr_t)g,
        (__attribute__((address_space(3))) unsigned int*)(unsigned int)(uintptr_t)lds,
        16, 0, 0);
}

// ---------------- prep: convert/permute constants into ws ----------------
__global__ void prep(const float* __restrict__ centres, const float* __restrict__ sigmas,
                     const float* __restrict__ W2, short* __restrict__ ws)
{
    int t = blockIdx.x * 256 + threadIdx.x;
    if (t < 12288) {
        // W2: [row 0..383][pc 0..31] short8; pc = c ^ (row&31)  (r12-verified layout)
        int row = t >> 5, pc = t & 31;
        int c = pc ^ (row & 31);
        short8 v = {0,0,0,0,0,0,0,0};
        if (row < DOUT) {
            int rr = row / 12, jj = row % 12;
            int fcl = rr / 3, kk = rr % 3;
            int o = fcl * 36 + jj * 3 + kk;            // fold output col permutation
            const float* src = W2 + o * HN + c * 8;
            #pragma unroll
            for (int i = 0; i < 8; ++i) v[i] = bf16_bits(src[i]);
        }
        *(short8*)(ws + (WS_W2 / 2) + t * 8) = v;
    } else if (t < 14336) {
        // cbf (r15-verified ns-fold): [row][p 0..7], p = c ^ (row&7)
        // k<60: nsq*c_k ; k=60,61: hi/lo of -0.5*nsq*c2 (B=1,1) ; k=62,63: -0.5*nsq (B=x2hi,x2lo)
        int j = t - 12288;
        int row = j >> 3, p = j & 7;
        int c = p ^ (row & 7);
        const float* cr = centres + row * DIN;
        float sg = sigmas[row];
        union { unsigned u; float f; } nq;
        nq.u = ((unsigned)(unsigned short)bf16_bits(2.f * sg * sg * 1.44269504088896340736f)) << 16;
        const float nsq = nq.f;                        // bf16-exact
        short8 v = {0,0,0,0,0,0,0,0};
        if (c < 7) {
            #pragma unroll
            for (int i = 0; i < 8; ++i) {
                int k = c * 8 + i;
                if (k < DIN) v[i] = bf16_bits(nsq * cr[k]);
            }
        } else {   // k = 56..63
            #pragma unroll
            for (int i = 0; i < 4; ++i) v[i] = bf16_bits(nsq * cr[56 + i]);
            float c2 = 0.f;
            #pragma unroll
            for (int d = 0; d < DIN; ++d) c2 = fmaf(cr[d], cr[d], c2);
            float T = -0.5f * nsq * c2;
            union { unsigned u; float f; } th;
            th.u = ((unsigned)(unsigned short)bf16_bits(T)) << 16;   // T_hi (bf16-exact)
            v[4] = bf16_bits(th.f);
            v[5] = bf16_bits(T - th.f);
            v[6] = bf16_bits(-0.5f * nsq);
            v[7] = v[6];
        }
        *(short8*)(ws + (WS_CBF / 2) + j * 8) = v;
    }
}

// ---- one 32-row x tile -> fold-packed bf16 B-fragments (r12-verified layout) ----
__device__ __forceinline__ void load_xtile(const float* __restrict__ x, int row0,
                                           int l31, int hi, short8 xb[4]) {
    const float* xr = x + (size_t)(row0 + l31) * DIN;
    f32x4 xa[4][2];
    #pragma unroll
    for (int kt = 0; kt < 4; ++kt) {
        int k0 = kt * 16 + hi * 8;
        xa[kt][0] = *(const f32x4*)(xr + k0);
        xa[kt][1] = (k0 + 4 < DIN) ? *(const f32x4*)(xr + k0 + 4) : (f32x4){0.f,0.f,0.f,0.f};
    }
    float p2 = 0.f;
    #pragma unroll
    for (int kt = 0; kt < 4; ++kt)
        #pragma unroll
        for (int h = 0; h < 2; ++h)
            #pragma unroll
            for (int i = 0; i < 4; ++i) p2 = fmaf(xa[kt][h][i], xa[kt][h][i], p2);
    float x2v = p2 + __shfl_xor(p2, 32);
    union { unsigned u; float f; } hb; hb.u = pk_bf16(x2v, 0.f) << 16;  // x2hi (bf16-exact)
    float x2lo = x2v - hb.f;
    #pragma unroll
    for (int kt = 0; kt < 4; ++kt) {
        union { u32x4 u; short8 s; } a;
        a.u[0] = pk_bf16(xa[kt][0][0], xa[kt][0][1]);
        a.u[1] = pk_bf16(xa[kt][0][2], xa[kt][0][3]);
        a.u[2] = pk_bf16(xa[kt][1][0], xa[kt][1][1]);
        a.u[3] = pk_bf16(xa[kt][1][2], xa[kt][1][3]);
        if (kt == 3) {   // hi lanes: k=60..63 -> B = {1, 1, x2hi, x2lo}
            a.u[2] = hi ? 0x3F803F80u : a.u[2];
            a.u[3] = hi ? pk_bf16(hb.f, x2lo) : a.u[3];
        }
        xb[kt] = a.s;
    }
}

// --- main: fused GEMM1->phi->GEMM2 per 32-h chunk; pw liveness 8 regs; no spill ---
__global__ __launch_bounds__(THREADS, 2)
void rbf_main(const float* __restrict__ x, const short* __restrict__ ws,
              float* __restrict__ out)
{
    __shared__ short8 w2h[6144];     // 96 KB: 192 rows x 32 chunks (this col-half)
    __shared__ short8 cbf[2048];     // 32 KB: ns-scaled centres + fold

    const int tid  = threadIdx.x;
    const int w    = tid >> 6;
    const int lane = tid & 63;
    const int l31  = lane & 31;
    const int hi   = lane >> 5;
    const int bid  = blockIdx.x;
    // XCD pair-swizzle (r12): bid and bid^8 share rows, differ in col-half
    const int f     = (bid >> 3) & 1;
    const int sbase = (bid & 7) | ((bid >> 4) << 3);   // 0..127, bijective

    // ---- stage everything once (async DMA), one barrier total ----
    #pragma unroll
    for (int i = 0; i < 12; ++i)
        gload16(ws + (WS_W2 / 2) + ((size_t)f * 6144 + i * THREADS + tid) * 8,
                (char*)w2h + (i * THREADS + tid) * 16);
    #pragma unroll
    for (int i = 0; i < 4; ++i)
        gload16(ws + (WS_CBF / 2) + (i * THREADS + tid) * 8, (char*)cbf + (i * THREADS + tid) * 16);

    // ---- iter-0 x before the barrier (hides x latency under staging drain) ----
    short8 xb[4];
    load_xtile(x, sbase * 1024 + w * 32, l31, hi, xb);

    __syncthreads();   // LDS resident; no barriers, no LDS writes after this

    for (int it = 0; it < 4; ++it) {
        const int rb = sbase * 1024 + it * 256 + w * 32;

        f32x16 acc2[6];
        #pragma unroll
        for (int nt = 0; nt < 6; ++nt) acc2[nt] = (f32x16){};

        // ---- fused h-sweep: 8 chunks of 32 h ----
        #pragma unroll
        for (int nt1 = 0; nt1 < 8; ++nt1) {
            // GEMM1 chunk: S[l31-row][32 h] with complete exponent (ns-fold)
            f32x16 a1 = (f32x16){};
            const int row = nt1 * 32 + l31;
            __builtin_amdgcn_s_setprio(1);
            #pragma unroll
            for (int kt = 0; kt < 4; ++kt) {
                short8 cf = cbf[row * 8 + ((kt * 2 + hi) ^ (row & 7))];
                a1 = __builtin_amdgcn_mfma_f32_32x32x16_bf16(cf, xb[kt], a1, 0, 0, 0);
            }
            __builtin_amdgcn_s_setprio(0);

            // phi = exp2(min(S,0)) -> packed bf16 words (8 regs, die this chunk)
            unsigned pwl[4][2];
            #pragma unroll
            for (int q = 0; q < 4; ++q) {
                float ph[4];
                #pragma unroll
                for (int j = 0; j < 4; ++j)
                    ph[j] = exp2f(fminf(a1[4 * q + j], 0.f));
                pwl[q][0] = pk_bf16(ph[0], ph[1]);
                pwl[q][1] = pk_bf16(ph[2], ph[3]);
            }

            // 2 GEMM2 k-steps consume pwl immediately (r12-verified permlane dir)
            #pragma unroll
            for (int m = 0; m < 2; ++m) {
                unsigned d0 = pwl[2 * m][0], s0 = pwl[2 * m + 1][0];
                unsigned d1 = pwl[2 * m][1], s1 = pwl[2 * m + 1][1];
                asm("v_permlane32_swap_b32 %0, %1" : "+v"(d0), "+v"(s0));
                asm("v_permlane32_swap_b32 %0, %1" : "+v"(d1), "+v"(s1));
                union { u32x4 u; short8 s; } bfr;
                bfr.u[0] = d0; bfr.u[1] = d1; bfr.u[2] = s0; bfr.u[3] = s1;
                const int ktg = nt1 * 2 + m;

                __builtin_amdgcn_s_setprio(1);
                #pragma unroll
                for (int nt = 0; nt < 6; ++nt) {
                    int lrow = nt * 32 + l31;
                    short8 wf = w2h[lrow * 32 + ((ktg * 2 + hi) ^ l31)];
                    acc2[nt] = __builtin_amdgcn_mfma_f32_32x32x16_bf16(wf, bfr.s, acc2[nt], 0, 0, 0);
                }
                __builtin_amdgcn_s_setprio(0);
            }
        }

        // ---- next iter's x (issued before stores; latency hides under store burst) ----
        if (it < 3)
            load_xtile(x, rb + 256, l31, hi, xb);

        // ---- stores (r12-verified pattern): row rb+l31, 4 cols per reg-quad ----
        {
            float* op = out + (size_t)(rb + l31) * DOUT;
            #pragma unroll
            for (int nt = 0; nt < 6; ++nt) {
                #pragma unroll
                for (int q = 0; q < 4; ++q) {
                    int col = f * 192 + nt * 32 + q * 8 + hi * 4;
                    if (col < DOUT) {
                        f32x4 v;
                        v[0] = acc2[nt][4 * q + 0]; v[1] = acc2[nt][4 * q + 1];
                        v[2] = acc2[nt][4 * q + 2]; v[3] = acc2[nt][4 * q + 3];
                        *(f32x4*)(op + col) = v;
                    }
                }
            }
        }
    }
}

extern "C" void kernel_launch(void* const* d_in, const int* in_sizes, int n_in,
                              void* d_out, int out_size, void* d_ws, size_t ws_size,
                              hipStream_t stream) {
    const float* x       = (const float*)d_in[0];
    const float* centres = (const float*)d_in[1];
    const float* sigmas  = (const float*)d_in[2];
    const float* W2      = (const float*)d_in[3];
    float* out = (float*)d_out;
    short* ws  = (short*)d_ws;                  // needs 229376 B
    prep<<<dim3(56), dim3(256), 0, stream>>>(centres, sigmas, W2, ws);
    rbf_main<<<dim3(256), dim3(THREADS), 0, stream>>>(x, ws, out);
}

// Round 17
// 63.066 us; speedup vs baseline: 1.7118x; 1.0008x over previous
//
#include <hip/hip_runtime.h>

#define THREADS 512
#define DIN 60
#define HN 256
#define DOUT 360

typedef __attribute__((ext_vector_type(8))) short short8;
typedef __attribute__((ext_vector_type(16))) float f32x16;
typedef __attribute__((ext_vector_type(4))) float f32x4;
typedef __attribute__((ext_vector_type(4))) unsigned int u32x4;

// d_ws layout (bytes); total 229376 B
#define WS_CBF   0            // 2048 * 16 B = 32768  (ns-scaled centres + fold, [row][p], p=c^(row&7))
#define WS_W2    32768        // [row 0..383][pc 0..31] short8, pc=c^(row&31) = 196608 B

__device__ __forceinline__ short bf16_bits(float f) {   // prep-side only
    union { float f; unsigned u; } v; v.f = f;
    unsigned r = (v.u + 0x7FFFu + ((v.u >> 16) & 1u)) >> 16;
    return (short)(unsigned short)r;
}

__device__ __forceinline__ unsigned pk_bf16(float a, float b) {
    unsigned r;
    asm("v_cvt_pk_bf16_f32 %0, %1, %2" : "=v"(r) : "v"(a), "v"(b));
    return r;   // low16 = bf16(a), high16 = bf16(b)
}

__device__ __forceinline__ void gload16(const void* g, void* lds) {
    __builtin_amdgcn_global_load_lds(
        (const __attribute__((address_space(1))) unsigned int*)(uintptr_t)g,
        (__attribute__((address_space(3))) unsigned int*)(unsigned int)(uintptr_t)lds,
        16, 0, 0);
}

// ---------------- prep: convert/permute constants into ws (r16 verbatim) ----------------
__global__ void prep(const float* __restrict__ centres, const float* __restrict__ sigmas,
                     const float* __restrict__ W2, short* __restrict__ ws)
{
    int t = blockIdx.x * 256 + threadIdx.x;
    if (t < 12288) {
        int row = t >> 5, pc = t & 31;
        int c = pc ^ (row & 31);
        short8 v = {0,0,0,0,0,0,0,0};
        if (row < DOUT) {
            int rr = row / 12, jj = row % 12;
            int fcl = rr / 3, kk = rr % 3;
            int o = fcl * 36 + jj * 3 + kk;            // fold output col permutation
            const float* src = W2 + o * HN + c * 8;
            #pragma unroll
            for (int i = 0; i < 8; ++i) v[i] = bf16_bits(src[i]);
        }
        *(short8*)(ws + (WS_W2 / 2) + t * 8) = v;
    } else if (t < 14336) {
        // cbf (ns-fold): k<60: nsq*c_k ; k=60,61: hi/lo of -0.5*nsq*c2 (B=1,1) ;
        //                k=62,63: -0.5*nsq (B=x2hi,x2lo)
        int j = t - 12288;
        int row = j >> 3, p = j & 7;
        int c = p ^ (row & 7);
        const float* cr = centres + row * DIN;
        float sg = sigmas[row];
        union { unsigned u; float f; } nq;
        nq.u = ((unsigned)(unsigned short)bf16_bits(2.f * sg * sg * 1.44269504088896340736f)) << 16;
        const float nsq = nq.f;                        // bf16-exact
        short8 v = {0,0,0,0,0,0,0,0};
        if (c < 7) {
            #pragma unroll
            for (int i = 0; i < 8; ++i) {
                int k = c * 8 + i;
                if (k < DIN) v[i] = bf16_bits(nsq * cr[k]);
            }
        } else {   // k = 56..63
            #pragma unroll
            for (int i = 0; i < 4; ++i) v[i] = bf16_bits(nsq * cr[56 + i]);
            float c2 = 0.f;
            #pragma unroll
            for (int d = 0; d < DIN; ++d) c2 = fmaf(cr[d], cr[d], c2);
            float T = -0.5f * nsq * c2;
            union { unsigned u; float f; } th;
            th.u = ((unsigned)(unsigned short)bf16_bits(T)) << 16;   // T_hi (bf16-exact)
            v[4] = bf16_bits(th.f);
            v[5] = bf16_bits(T - th.f);
            v[6] = bf16_bits(-0.5f * nsq);
            v[7] = v[6];
        }
        *(short8*)(ws + (WS_CBF / 2) + j * 8) = v;
    }
}

// ---- T14 split: raw loads (issue-early) / pack (late, data already resident) ----
__device__ __forceinline__ void xload(const float* __restrict__ x, int row0,
                                      int l31, int hi, f32x4 xa[4][2]) {
    const float* xr = x + (size_t)(row0 + l31) * DIN;
    #pragma unroll
    for (int kt = 0; kt < 4; ++kt) {
        int k0 = kt * 16 + hi * 8;
        xa[kt][0] = *(const f32x4*)(xr + k0);
        xa[kt][1] = (k0 + 4 < DIN) ? *(const f32x4*)(xr + k0 + 4) : (f32x4){0.f,0.f,0.f,0.f};
    }
}

__device__ __forceinline__ void xpack(const f32x4 xa[4][2], int hi, short8 xb[4]) {
    float p2 = 0.f;
    #pragma unroll
    for (int kt = 0; kt < 4; ++kt)
        #pragma unroll
        for (int h = 0; h < 2; ++h)
            #pragma unroll
            for (int i = 0; i < 4; ++i) p2 = fmaf(xa[kt][h][i], xa[kt][h][i], p2);
    float x2v = p2 + __shfl_xor(p2, 32);
    union { unsigned u; float f; } hb; hb.u = pk_bf16(x2v, 0.f) << 16;  // x2hi (bf16-exact)
    float x2lo = x2v - hb.f;
    #pragma unroll
    for (int kt = 0; kt < 4; ++kt) {
        union { u32x4 u; short8 s; } a;
        a.u[0] = pk_bf16(xa[kt][0][0], xa[kt][0][1]);
        a.u[1] = pk_bf16(xa[kt][0][2], xa[kt][0][3]);
        a.u[2] = pk_bf16(xa[kt][1][0], xa[kt][1][1]);
        a.u[3] = pk_bf16(xa[kt][1][2], xa[kt][1][3]);
        if (kt == 3) {   // hi lanes: k=60..63 -> B = {1, 1, x2hi, x2lo}
            a.u[2] = hi ? 0x3F803F80u : a.u[2];
            a.u[3] = hi ? pk_bf16(hb.f, x2lo) : a.u[3];
        }
        xb[kt] = a.s;
    }
}

// --- main: r16 fused structure + wave iteration stagger + T14 x prefetch split ---
__global__ __launch_bounds__(THREADS, 2)
void rbf_main(const float* __restrict__ x, const short* __restrict__ ws,
              float* __restrict__ out)
{
    __shared__ short8 w2h[6144];     // 96 KB: 192 rows x 32 chunks (this col-half)
    __shared__ short8 cbf[2048];     // 32 KB: ns-scaled centres + fold

    const int tid  = threadIdx.x;
    const int w    = tid >> 6;
    const int lane = tid & 63;
    const int l31  = lane & 31;
    const int hi   = lane >> 5;
    const int bid  = blockIdx.x;
    // XCD pair-swizzle (r12): bid and bid^8 share rows, differ in col-half
    const int f     = (bid >> 3) & 1;
    const int sbase = (bid & 7) | ((bid >> 4) << 3);   // 0..127, bijective
    const int stg   = w & 3;                           // per-wave phase stagger

    // ---- stage everything once (async DMA), one barrier total ----
    #pragma unroll
    for (int i = 0; i < 12; ++i)
        gload16(ws + (WS_W2 / 2) + ((size_t)f * 6144 + i * THREADS + tid) * 8,
                (char*)w2h + (i * THREADS + tid) * 16);
    #pragma unroll
    for (int i = 0; i < 4; ++i)
        gload16(ws + (WS_CBF / 2) + (i * THREADS + tid) * 8, (char*)cbf + (i * THREADS + tid) * 16);

    // ---- first staggered iteration's x, issued before the barrier ----
    f32x4 xa[4][2];
    xload(x, sbase * 1024 + stg * 256 + w * 32, l31, hi, xa);

    __syncthreads();   // LDS resident; no barriers, no LDS writes after this

    for (int it = 0; it < 4; ++it) {
        const int myit = (it + stg) & 3;
        const int rb   = sbase * 1024 + myit * 256 + w * 32;

        // ---- pack xb (data arrived during previous h-sweep); then issue next loads ----
        short8 xb[4];
        xpack(xa, hi, xb);
        if (it < 3)
            xload(x, sbase * 1024 + (((it + 1) + stg) & 3) * 256 + w * 32, l31, hi, xa);

        f32x16 acc2[6];
        #pragma unroll
        for (int nt = 0; nt < 6; ++nt) acc2[nt] = (f32x16){};

        // ---- fused h-sweep: 8 chunks of 32 h (r16 verbatim) ----
        #pragma unroll
        for (int nt1 = 0; nt1 < 8; ++nt1) {
            f32x16 a1 = (f32x16){};
            const int row = nt1 * 32 + l31;
            __builtin_amdgcn_s_setprio(1);
            #pragma unroll
            for (int kt = 0; kt < 4; ++kt) {
                short8 cf = cbf[row * 8 + ((kt * 2 + hi) ^ (row & 7))];
                a1 = __builtin_amdgcn_mfma_f32_32x32x16_bf16(cf, xb[kt], a1, 0, 0, 0);
            }
            __builtin_amdgcn_s_setprio(0);

            unsigned pwl[4][2];
            #pragma unroll
            for (int q = 0; q < 4; ++q) {
                float ph[4];
                #pragma unroll
                for (int j = 0; j < 4; ++j)
                    ph[j] = exp2f(fminf(a1[4 * q + j], 0.f));
                pwl[q][0] = pk_bf16(ph[0], ph[1]);
                pwl[q][1] = pk_bf16(ph[2], ph[3]);
            }

            #pragma unroll
            for (int m = 0; m < 2; ++m) {
                unsigned d0 = pwl[2 * m][0], s0 = pwl[2 * m + 1][0];
                unsigned d1 = pwl[2 * m][1], s1 = pwl[2 * m + 1][1];
                asm("v_permlane32_swap_b32 %0, %1" : "+v"(d0), "+v"(s0));
                asm("v_permlane32_swap_b32 %0, %1" : "+v"(d1), "+v"(s1));
                union { u32x4 u; short8 s; } bfr;
                bfr.u[0] = d0; bfr.u[1] = d1; bfr.u[2] = s0; bfr.u[3] = s1;
                const int ktg = nt1 * 2 + m;

                __builtin_amdgcn_s_setprio(1);
                #pragma unroll
                for (int nt = 0; nt < 6; ++nt) {
                    int lrow = nt * 32 + l31;
                    short8 wf = w2h[lrow * 32 + ((ktg * 2 + hi) ^ l31)];
                    acc2[nt] = __builtin_amdgcn_mfma_f32_32x32x16_bf16(wf, bfr.s, acc2[nt], 0, 0, 0);
                }
                __builtin_amdgcn_s_setprio(0);
            }
        }

        // ---- stores immediately after GEMM2 (no x-wait in front of them) ----
        {
            float* op = out + (size_t)(rb + l31) * DOUT;
            #pragma unroll
            for (int nt = 0; nt < 6; ++nt) {
                #pragma unroll
                for (int q = 0; q < 4; ++q) {
                    int col = f * 192 + nt * 32 + q * 8 + hi * 4;
                    if (col < DOUT) {
                        f32x4 v;
                        v[0] = acc2[nt][4 * q + 0]; v[1] = acc2[nt][4 * q + 1];
                        v[2] = acc2[nt][4 * q + 2]; v[3] = acc2[nt][4 * q + 3];
                        *(f32x4*)(op + col) = v;
                    }
                }
            }
        }
    }
}

extern "C" void kernel_launch(void* const* d_in, const int* in_sizes, int n_in,
                              void* d_out, int out_size, void* d_ws, size_t ws_size,
                              hipStream_t stream) {
    const float* x       = (const float*)d_in[0];
    const float* centres = (const float*)d_in[1];
    const float* sigmas  = (const float*)d_in[2];
    const float* W2      = (const float*)d_in[3];
    float* out = (float*)d_out;
    short* ws  = (short*)d_ws;                  // needs 229376 B
    prep<<<dim3(56), dim3(256), 0, stream>>>(centres, sigmas, W2, ws);
    rbf_main<<<dim3(256), dim3(THREADS), 0, stream>>>(x, ws, out);
}

// Round 18
// 63.020 us; speedup vs baseline: 1.7130x; 1.0007x over previous
//
#include <hip/hip_runtime.h>

#define THREADS 512
#define DIN 60
#define HN 256
#define DOUT 360

typedef __attribute__((ext_vector_type(8))) short short8;
typedef __attribute__((ext_vector_type(16))) float f32x16;
typedef __attribute__((ext_vector_type(4))) float f32x4;
typedef __attribute__((ext_vector_type(4))) unsigned int u32x4;

// d_ws layout (bytes); total 229376 B
#define WS_CBF   0            // 2048 * 16 B = 32768  (ns-scaled centres + fold, [row][p], p=c^(row&7))
#define WS_W2    32768        // [row 0..383][pc 0..31] short8, pc=c^(row&31) = 196608 B

__device__ __forceinline__ short bf16_bits(float f) {   // prep-side only
    union { float f; unsigned u; } v; v.f = f;
    unsigned r = (v.u + 0x7FFFu + ((v.u >> 16) & 1u)) >> 16;
    return (short)(unsigned short)r;
}

__device__ __forceinline__ unsigned pk_bf16(float a, float b) {
    unsigned r;
    asm("v_cvt_pk_bf16_f32 %0, %1, %2" : "=v"(r) : "v"(a), "v"(b));
    return r;   // low16 = bf16(a), high16 = bf16(b)
}

__device__ __forceinline__ void gload16(const void* g, void* lds) {
    __builtin_amdgcn_global_load_lds(
        (const __attribute__((address_space(1))) unsigned int*)(uintptr_t)g,
        (__attribute__((address_space(3))) unsigned int*)(unsigned int)(uintptr_t)lds,
        16, 0, 0);
}

// ---------------- prep: convert/permute constants into ws (r16 verbatim) ----------------
__global__ void prep(const float* __restrict__ centres, const float* __restrict__ sigmas,
                     const float* __restrict__ W2, short* __restrict__ ws)
{
    int t = blockIdx.x * 256 + threadIdx.x;
    if (t < 12288) {
        int row = t >> 5, pc = t & 31;
        int c = pc ^ (row & 31);
        short8 v = {0,0,0,0,0,0,0,0};
        if (row < DOUT) {
            int rr = row / 12, jj = row % 12;
            int fcl = rr / 3, kk = rr % 3;
            int o = fcl * 36 + jj * 3 + kk;            // fold output col permutation
            const float* src = W2 + o * HN + c * 8;
            #pragma unroll
            for (int i = 0; i < 8; ++i) v[i] = bf16_bits(src[i]);
        }
        *(short8*)(ws + (WS_W2 / 2) + t * 8) = v;
    } else if (t < 14336) {
        // cbf (ns-fold): k<60: nsq*c_k ; k=60,61: hi/lo of -0.5*nsq*c2 (B=1,1) ;
        //                k=62,63: -0.5*nsq (B=x2hi,x2lo)
        int j = t - 12288;
        int row = j >> 3, p = j & 7;
        int c = p ^ (row & 7);
        const float* cr = centres + row * DIN;
        float sg = sigmas[row];
        union { unsigned u; float f; } nq;
        nq.u = ((unsigned)(unsigned short)bf16_bits(2.f * sg * sg * 1.44269504088896340736f)) << 16;
        const float nsq = nq.f;                        // bf16-exact
        short8 v = {0,0,0,0,0,0,0,0};
        if (c < 7) {
            #pragma unroll
            for (int i = 0; i < 8; ++i) {
                int k = c * 8 + i;
                if (k < DIN) v[i] = bf16_bits(nsq * cr[k]);
            }
        } else {   // k = 56..63
            #pragma unroll
            for (int i = 0; i < 4; ++i) v[i] = bf16_bits(nsq * cr[56 + i]);
            float c2 = 0.f;
            #pragma unroll
            for (int d = 0; d < DIN; ++d) c2 = fmaf(cr[d], cr[d], c2);
            float T = -0.5f * nsq * c2;
            union { unsigned u; float f; } th;
            th.u = ((unsigned)(unsigned short)bf16_bits(T)) << 16;   // T_hi (bf16-exact)
            v[4] = bf16_bits(th.f);
            v[5] = bf16_bits(T - th.f);
            v[6] = bf16_bits(-0.5f * nsq);
            v[7] = v[6];
        }
        *(short8*)(ws + (WS_CBF / 2) + j * 8) = v;
    }
}

// ---- one 32-row x tile -> fold-packed bf16 B-fragments (r12-verified layout) ----
__device__ __forceinline__ void load_xtile(const float* __restrict__ x, int row0,
                                           int l31, int hi, short8 xb[4]) {
    const float* xr = x + (size_t)(row0 + l31) * DIN;
    f32x4 xa[4][2];
    #pragma unroll
    for (int kt = 0; kt < 4; ++kt) {
        int k0 = kt * 16 + hi * 8;
        xa[kt][0] = *(const f32x4*)(xr + k0);
        xa[kt][1] = (k0 + 4 < DIN) ? *(const f32x4*)(xr + k0 + 4) : (f32x4){0.f,0.f,0.f,0.f};
    }
    float p2 = 0.f;
    #pragma unroll
    for (int kt = 0; kt < 4; ++kt)
        #pragma unroll
        for (int h = 0; h < 2; ++h)
            #pragma unroll
            for (int i = 0; i < 4; ++i) p2 = fmaf(xa[kt][h][i], xa[kt][h][i], p2);
    float x2v = p2 + __shfl_xor(p2, 32);
    union { unsigned u; float f; } hb; hb.u = pk_bf16(x2v, 0.f) << 16;  // x2hi (bf16-exact)
    float x2lo = x2v - hb.f;
    #pragma unroll
    for (int kt = 0; kt < 4; ++kt) {
        union { u32x4 u; short8 s; } a;
        a.u[0] = pk_bf16(xa[kt][0][0], xa[kt][0][1]);
        a.u[1] = pk_bf16(xa[kt][0][2], xa[kt][0][3]);
        a.u[2] = pk_bf16(xa[kt][1][0], xa[kt][1][1]);
        a.u[3] = pk_bf16(xa[kt][1][2], xa[kt][1][3]);
        if (kt == 3) {   // hi lanes: k=60..63 -> B = {1, 1, x2hi, x2lo}
            a.u[2] = hi ? 0x3F803F80u : a.u[2];
            a.u[3] = hi ? pk_bf16(hb.f, x2lo) : a.u[3];
        }
        xb[kt] = a.s;
    }
}

// --- main: r16 fused structure; occupancy PINNED at 2 waves/EU so the allocator
//     may use up to 256 VGPRs (launch_bounds-only builds clamped at 128 -> spill) ---
__global__ __attribute__((amdgpu_flat_work_group_size(THREADS, THREADS),
                          amdgpu_waves_per_eu(2, 2)))
void rbf_main(const float* __restrict__ x, const short* __restrict__ ws,
              float* __restrict__ out)
{
    __shared__ short8 w2h[6144];     // 96 KB: 192 rows x 32 chunks (this col-half)
    __shared__ short8 cbf[2048];     // 32 KB: ns-scaled centres + fold

    const int tid  = threadIdx.x;
    const int w    = tid >> 6;
    const int lane = tid & 63;
    const int l31  = lane & 31;
    const int hi   = lane >> 5;
    const int bid  = blockIdx.x;
    // XCD pair-swizzle (r12): bid and bid^8 share rows, differ in col-half
    const int f     = (bid >> 3) & 1;
    const int sbase = (bid & 7) | ((bid >> 4) << 3);   // 0..127, bijective

    // ---- stage everything once (async DMA), one barrier total ----
    #pragma unroll
    for (int i = 0; i < 12; ++i)
        gload16(ws + (WS_W2 / 2) + ((size_t)f * 6144 + i * THREADS + tid) * 8,
                (char*)w2h + (i * THREADS + tid) * 16);
    #pragma unroll
    for (int i = 0; i < 4; ++i)
        gload16(ws + (WS_CBF / 2) + (i * THREADS + tid) * 8, (char*)cbf + (i * THREADS + tid) * 16);

    // ---- iter-0 x before the barrier (hides x latency under staging drain) ----
    short8 xb[4];
    load_xtile(x, sbase * 1024 + w * 32, l31, hi, xb);

    __syncthreads();   // LDS resident; no barriers, no LDS writes after this

    for (int it = 0; it < 4; ++it) {
        const int rb = sbase * 1024 + it * 256 + w * 32;

        f32x16 acc2[6];
        #pragma unroll
        for (int nt = 0; nt < 6; ++nt) acc2[nt] = (f32x16){};

        // ---- fused h-sweep: 8 chunks of 32 h ----
        #pragma unroll
        for (int nt1 = 0; nt1 < 8; ++nt1) {
            f32x16 a1 = (f32x16){};
            const int row = nt1 * 32 + l31;
            __builtin_amdgcn_s_setprio(1);
            #pragma unroll
            for (int kt = 0; kt < 4; ++kt) {
                short8 cf = cbf[row * 8 + ((kt * 2 + hi) ^ (row & 7))];
                a1 = __builtin_amdgcn_mfma_f32_32x32x16_bf16(cf, xb[kt], a1, 0, 0, 0);
            }
            __builtin_amdgcn_s_setprio(0);

            unsigned pwl[4][2];
            #pragma unroll
            for (int q = 0; q < 4; ++q) {
                float ph[4];
                #pragma unroll
                for (int j = 0; j < 4; ++j)
                    ph[j] = exp2f(fminf(a1[4 * q + j], 0.f));
                pwl[q][0] = pk_bf16(ph[0], ph[1]);
                pwl[q][1] = pk_bf16(ph[2], ph[3]);
            }

            #pragma unroll
            for (int m = 0; m < 2; ++m) {
                unsigned d0 = pwl[2 * m][0], s0 = pwl[2 * m + 1][0];
                unsigned d1 = pwl[2 * m][1], s1 = pwl[2 * m + 1][1];
                asm("v_permlane32_swap_b32 %0, %1" : "+v"(d0), "+v"(s0));
                asm("v_permlane32_swap_b32 %0, %1" : "+v"(d1), "+v"(s1));
                union { u32x4 u; short8 s; } bfr;
                bfr.u[0] = d0; bfr.u[1] = d1; bfr.u[2] = s0; bfr.u[3] = s1;
                const int ktg = nt1 * 2 + m;

                __builtin_amdgcn_s_setprio(1);
                #pragma unroll
                for (int nt = 0; nt < 6; ++nt) {
                    int lrow = nt * 32 + l31;
                    short8 wf = w2h[lrow * 32 + ((ktg * 2 + hi) ^ l31)];
                    acc2[nt] = __builtin_amdgcn_mfma_f32_32x32x16_bf16(wf, bfr.s, acc2[nt], 0, 0, 0);
                }
                __builtin_amdgcn_s_setprio(0);
            }
        }

        // ---- next iter's x (issued before stores; latency hides under store burst) ----
        if (it < 3)
            load_xtile(x, rb + 256, l31, hi, xb);

        // ---- stores (r12-verified pattern): row rb+l31, 4 cols per reg-quad ----
        {
            float* op = out + (size_t)(rb + l31) * DOUT;
            #pragma unroll
            for (int nt = 0; nt < 6; ++nt) {
                #pragma unroll
                for (int q = 0; q < 4; ++q) {
                    int col = f * 192 + nt * 32 + q * 8 + hi * 4;
                    if (col < DOUT) {
                        f32x4 v;
                        v[0] = acc2[nt][4 * q + 0]; v[1] = acc2[nt][4 * q + 1];
                        v[2] = acc2[nt][4 * q + 2]; v[3] = acc2[nt][4 * q + 3];
                        *(f32x4*)(op + col) = v;
                    }
                }
            }
        }
    }
}

extern "C" void kernel_launch(void* const* d_in, const int* in_sizes, int n_in,
                              void* d_out, int out_size, void* d_ws, size_t ws_size,
                              hipStream_t stream) {
    const float* x       = (const float*)d_in[0];
    const float* centres = (const float*)d_in[1];
    const float* sigmas  = (const float*)d_in[2];
    const float* W2      = (const float*)d_in[3];
    float* out = (float*)d_out;
    short* ws  = (short*)d_ws;                  // needs 229376 B
    prep<<<dim3(56), dim3(256), 0, stream>>>(centres, sigmas, W2, ws);
    rbf_main<<<dim3(256), dim3(THREADS), 0, stream>>>(x, ws, out);
}